// Round 6
// baseline (277.840 us; speedup 1.0000x reference)
//
#include <hip/hip_runtime.h>
#include <math.h>

#define B   64
#define M   1024
#define RNN 1024
#define H   512
#define D   2048

#define NCHUNK 16
#define CROWS  (M / NCHUNK)   // 64 rows per block
#define RPW    (CROWS / 4)    // 16 rows per wave (phase 1)

// tanh(x) = sign(x) * (1 - e^{-2|x|}) / (1 + e^{-2|x|}); rcp via v_rcp_f32 (~1 ulp)
__device__ __forceinline__ float fast_tanh(float x) {
    float ax = fabsf(x);
    float t  = __expf(-2.0f * ax);
    float r  = (1.0f - t) * __builtin_amdgcn_rcpf(1.0f + t);
    return copysignf(r, x);
}

// Tiled wah = h @ W^T. grid (H/8, B/16), 256 threads.
// Each wave holds 2 W rows in registers; 16 h rows staged in LDS (64KB).
// Logical traffic ~10MB (vs 128MB for one-wave-per-output). Also zeroes tickets.
__global__ __launch_bounds__(256) void k_wah(const float* __restrict__ h,
                                             const float* __restrict__ W,
                                             float* __restrict__ wah,
                                             int* __restrict__ tickets) {
    if (blockIdx.x == 0 && blockIdx.y == 0 && threadIdx.x < B)
        tickets[threadIdx.x] = 0;

    const int tid = threadIdx.x, lane = tid & 63, w = tid >> 6;
    const int bt = blockIdx.y * 16;
    const int j0 = blockIdx.x * 8 + w * 2;

    __shared__ float s_h[16 * RNN];        // 64KB
    const float4* h4  = (const float4*)(h + (size_t)bt * RNN);
    float4*       sh4 = (float4*)s_h;
#pragma unroll
    for (int k = 0; k < 16; ++k)
        sh4[tid + k * 256] = h4[tid + k * 256];

    const float4* Wa = (const float4*)(W + (size_t)j0 * RNN);
    const float4* Wb = (const float4*)(W + (size_t)(j0 + 1) * RNN);
    float4 wa[4], wb[4];
#pragma unroll
    for (int k = 0; k < 4; ++k) { wa[k] = Wa[lane + 64 * k]; wb[k] = Wb[lane + 64 * k]; }
    __syncthreads();

    for (int b = 0; b < 16; ++b) {
        float d0 = 0.0f, d1 = 0.0f;
#pragma unroll
        for (int k = 0; k < 4; ++k) {
            float4 hv = sh4[b * 256 + lane + 64 * k];
            d0 += hv.x * wa[k].x + hv.y * wa[k].y + hv.z * wa[k].z + hv.w * wa[k].w;
            d1 += hv.x * wb[k].x + hv.y * wb[k].y + hv.z * wb[k].z + hv.w * wb[k].w;
        }
#pragma unroll
        for (int off = 32; off > 0; off >>= 1) {
            d0 += __shfl_xor(d0, off);
            d1 += __shfl_xor(d1, off);
        }
        if (lane == 0)
            *(float2*)(wah + (size_t)(bt + b) * H + j0) = make_float2(d0, d1);
    }
}

// Fused: phase 1 computes unnormalized weights w=exp(logit) for 64 rows
// (no max subtraction; logits O(+-5), f32-safe, ratio identical).
// Phase 2 ballot-compacts (pads duplicate an already-read row with alpha=0 ->
// L1-hit, no extra HBM) and streams feats into partial accumulators.
// Last block per b (device-scope ticket) reduces partials + Z -> out.
__global__ __launch_bounds__(256) void k_fused(const float* __restrict__ wah,
                                               const float* __restrict__ p_att,
                                               const int* __restrict__ mask,
                                               const float* __restrict__ w_alpha,
                                               const float* __restrict__ feats,
                                               float* __restrict__ partial,
                                               float* __restrict__ zpart,
                                               int* __restrict__ tickets,
                                               float* __restrict__ out) {
    const int b   = blockIdx.x;
    const int c   = blockIdx.y;
    const int tid = threadIdx.x;
    const int lane = tid & 63;
    const int w    = tid >> 6;

    __shared__ float          s_w[CROWS];
    __shared__ float          s_zred[4];
    __shared__ unsigned short s_idx[CROWS + 4];
    __shared__ float          s_val[CROWS + 4];
    __shared__ int            s_cntreal;
    __shared__ int            s_ticket;

    const float4* wh4 = (const float4*)(wah + (size_t)b * H);
    const float4* wa4 = (const float4*)w_alpha;
    float4 wh0 = wh4[lane], wh1 = wh4[lane + 64];
    float4 wa0 = wa4[lane], wa1 = wa4[lane + 64];

    const int     m0   = c * CROWS;
    const int*    mrow = mask + (size_t)b * M + m0;
    const float4* pb4  = (const float4*)(p_att + ((size_t)b * M + m0) * H);

    float zsum = 0.0f;
    for (int r = w * RPW; r < w * RPW + RPW; ++r) {
        float e = 0.0f;
        if (mrow[r] != 0) {                       // wave-uniform branch
            float4 p0 = pb4[(size_t)r * (H / 4) + lane];
            float4 p1 = pb4[(size_t)r * (H / 4) + 64 + lane];
            float s = fast_tanh(p0.x + wh0.x) * wa0.x
                    + fast_tanh(p0.y + wh0.y) * wa0.y
                    + fast_tanh(p0.z + wh0.z) * wa0.z
                    + fast_tanh(p0.w + wh0.w) * wa0.w
                    + fast_tanh(p1.x + wh1.x) * wa1.x
                    + fast_tanh(p1.y + wh1.y) * wa1.y
                    + fast_tanh(p1.z + wh1.z) * wa1.z
                    + fast_tanh(p1.w + wh1.w) * wa1.w;
#pragma unroll
            for (int off = 32; off > 0; off >>= 1)
                s += __shfl_xor(s, off);
            e = __expf(s);                        // uniform across lanes
        }
        if (lane == 0) s_w[r] = e;
        zsum += e;
    }
    if (lane == 0) s_zred[w] = zsum;
    __syncthreads();
    if (tid == 0)
        zpart[(size_t)c * B + b] = (s_zred[0] + s_zred[1]) + (s_zred[2] + s_zred[3]);

    // ordered compaction (wave 0)
    if (tid < CROWS) {
        float a = s_w[tid];
        bool pred = (a != 0.0f);
        unsigned long long bal = __ballot(pred);
        int pos = __popcll(bal & ((1ull << lane) - 1ull));
        if (pred) { s_idx[pos] = (unsigned short)tid; s_val[pos] = a; }
        if (lane == 0) s_cntreal = __popcll(bal);
    }
    __syncthreads();
    const int cnt = s_cntreal;
    const int n   = (cnt + 3) & ~3;
    if (tid >= cnt && tid < n) {          // pad: duplicate a real row, alpha=0
        s_idx[tid] = (cnt > 0) ? s_idx[cnt - 1] : (unsigned short)0;
        s_val[tid] = 0.0f;
    }
    __syncthreads();

    // phase 2: wave w owns d-slice [w*512, (w+1)*512); 8 loads in flight
    const float4* fb4 = (const float4*)(feats + ((size_t)b * M + m0) * D)
                        + (size_t)w * 128 + lane;
    float4 acc0 = {0.f, 0.f, 0.f, 0.f}, acc1 = {0.f, 0.f, 0.f, 0.f};
    for (int i = 0; i < n; i += 4) {
        int   r0 = s_idx[i],     r1 = s_idx[i + 1];
        int   r2 = s_idx[i + 2], r3 = s_idx[i + 3];
        float v0 = s_val[i],     v1 = s_val[i + 1];
        float v2 = s_val[i + 2], v3 = s_val[i + 3];
        const float4* q0 = fb4 + (size_t)r0 * (D / 4);
        const float4* q1 = fb4 + (size_t)r1 * (D / 4);
        const float4* q2 = fb4 + (size_t)r2 * (D / 4);
        const float4* q3 = fb4 + (size_t)r3 * (D / 4);
        float4 f00 = q0[0], f01 = q0[64];
        float4 f10 = q1[0], f11 = q1[64];
        float4 f20 = q2[0], f21 = q2[64];
        float4 f30 = q3[0], f31 = q3[64];
        acc0.x += v0 * f00.x; acc0.y += v0 * f00.y; acc0.z += v0 * f00.z; acc0.w += v0 * f00.w;
        acc1.x += v0 * f01.x; acc1.y += v0 * f01.y; acc1.z += v0 * f01.z; acc1.w += v0 * f01.w;
        acc0.x += v1 * f10.x; acc0.y += v1 * f10.y; acc0.z += v1 * f10.z; acc0.w += v1 * f10.w;
        acc1.x += v1 * f11.x; acc1.y += v1 * f11.y; acc1.z += v1 * f11.z; acc1.w += v1 * f11.w;
        acc0.x += v2 * f20.x; acc0.y += v2 * f20.y; acc0.z += v2 * f20.z; acc0.w += v2 * f20.w;
        acc1.x += v2 * f21.x; acc1.y += v2 * f21.y; acc1.z += v2 * f21.z; acc1.w += v2 * f21.w;
        acc0.x += v3 * f30.x; acc0.y += v3 * f30.y; acc0.z += v3 * f30.z; acc0.w += v3 * f30.w;
        acc1.x += v3 * f31.x; acc1.y += v3 * f31.y; acc1.z += v3 * f31.z; acc1.w += v3 * f31.w;
    }
    float4* ob = (float4*)(partial + ((size_t)c * B + b) * D) + (size_t)w * 128 + lane;
    ob[0]  = acc0;
    ob[64] = acc1;

    // ---- last block per b reduces (split-K pattern; fixed sum order -> deterministic)
    __threadfence();                               // release partial/zpart writes
    if (tid == 0) s_ticket = atomicAdd(&tickets[b], 1);
    __syncthreads();
    if (s_ticket != NCHUNK - 1) return;
    __threadfence();                               // acquire others' writes

    float Z = 0.0f;
#pragma unroll
    for (int c2 = 0; c2 < NCHUNK; ++c2)
        Z += zpart[(size_t)c2 * B + b];
    const float invZ = 1.0f / Z;

    const float4* p4 = (const float4*)partial;
#pragma unroll
    for (int t = tid; t < D / 4; t += 256) {
        float4 s = {0.f, 0.f, 0.f, 0.f};
#pragma unroll
        for (int c2 = 0; c2 < NCHUNK; ++c2) {
            float4 v = p4[((size_t)c2 * B + b) * (D / 4) + t];
            s.x += v.x; s.y += v.y; s.z += v.z; s.w += v.w;
        }
        float4 r = {s.x * invZ, s.y * invZ, s.z * invZ, s.w * invZ};
        ((float4*)out)[(size_t)b * (D / 4) + t] = r;
    }
}

extern "C" void kernel_launch(void* const* d_in, const int* in_sizes, int n_in,
                              void* d_out, int out_size, void* d_ws, size_t ws_size,
                              hipStream_t stream) {
    const float* h       = (const float*)d_in[0];
    const float* feats   = (const float*)d_in[1];
    const int*   mask    = (const int*)d_in[2];
    const float* p_att   = (const float*)d_in[3];
    const float* W_ah    = (const float*)d_in[4];
    const float* w_alpha = (const float*)d_in[5];
    float* out = (float*)d_out;

    float* ws      = (float*)d_ws;
    float* wah     = ws;                   // B*H floats
    float* zpart   = wah + B * H;          // NCHUNK*B floats
    float* partial = zpart + NCHUNK * B;   // NCHUNK*B*D floats (8MB)
    int*   tickets = (int*)(partial + (size_t)NCHUNK * B * D);   // B ints

    k_wah  <<<dim3(H / 8, B / 16), 256, 0, stream>>>(h, W_ah, wah, tickets);
    k_fused<<<dim3(B, NCHUNK), 256, 0, stream>>>(wah, p_att, mask, w_alpha, feats,
                                                 partial, zpart, tickets, out);
}

// Round 7
// 78.630 us; speedup vs baseline: 3.5335x; 3.5335x over previous
//
#include <hip/hip_runtime.h>
#include <math.h>

#define B   64
#define M   1024
#define RNN 1024
#define H   512
#define D   2048

#define NCHUNK 16
#define CROWS  (M / NCHUNK)   // 64 rows per block
#define RPW    (CROWS / 4)    // 16 rows per wave (phase 1)

// tanh(x) = sign(x) * (1 - e^{-2|x|}) / (1 + e^{-2|x|}); rcp via v_rcp_f32 (~1 ulp)
__device__ __forceinline__ float fast_tanh(float x) {
    float ax = fabsf(x);
    float t  = __expf(-2.0f * ax);
    float r  = (1.0f - t) * __builtin_amdgcn_rcpf(1.0f + t);
    return copysignf(r, x);
}

// Tiled wah = h @ W^T. grid (H/8, B/16), 256 threads.
// Each wave holds 2 W rows in registers; 16 h rows staged in LDS (64KB).
// Logical traffic ~10MB (vs 128MB one-wave-per-output).
__global__ __launch_bounds__(256) void k_wah(const float* __restrict__ h,
                                             const float* __restrict__ W,
                                             float* __restrict__ wah) {
    const int tid = threadIdx.x, lane = tid & 63, w = tid >> 6;
    const int bt = blockIdx.y * 16;
    const int j0 = blockIdx.x * 8 + w * 2;

    __shared__ float s_h[16 * RNN];        // 64KB
    const float4* h4  = (const float4*)(h + (size_t)bt * RNN);
    float4*       sh4 = (float4*)s_h;
#pragma unroll
    for (int k = 0; k < 16; ++k)
        sh4[tid + k * 256] = h4[tid + k * 256];

    const float4* Wa = (const float4*)(W + (size_t)j0 * RNN);
    const float4* Wb = (const float4*)(W + (size_t)(j0 + 1) * RNN);
    float4 wa[4], wb[4];
#pragma unroll
    for (int k = 0; k < 4; ++k) { wa[k] = Wa[lane + 64 * k]; wb[k] = Wb[lane + 64 * k]; }
    __syncthreads();

    for (int b = 0; b < 16; ++b) {
        float d0 = 0.0f, d1 = 0.0f;
#pragma unroll
        for (int k = 0; k < 4; ++k) {
            float4 hv = sh4[b * 256 + lane + 64 * k];
            d0 += hv.x * wa[k].x + hv.y * wa[k].y + hv.z * wa[k].z + hv.w * wa[k].w;
            d1 += hv.x * wb[k].x + hv.y * wb[k].y + hv.z * wb[k].z + hv.w * wb[k].w;
        }
#pragma unroll
        for (int off = 32; off > 0; off >>= 1) {
            d0 += __shfl_xor(d0, off);
            d1 += __shfl_xor(d1, off);
        }
        if (lane == 0)
            *(float2*)(wah + (size_t)(bt + b) * H + j0) = make_float2(d0, d1);
    }
}

// Fused: phase 1 computes unnormalized weights w=exp(logit) for 64 rows
// (no max subtraction; logits O(+-5), f32-safe, ratio identical).
// Phase 2 ballot-compacts (pads duplicate an already-read row with alpha=0 ->
// cache hit, no extra HBM) and streams feats into partial accumulators.
// NO device fences here -- round 6 showed __threadfence per block costs ~200us.
__global__ __launch_bounds__(256) void k_fused(const float* __restrict__ wah,
                                               const float* __restrict__ p_att,
                                               const int* __restrict__ mask,
                                               const float* __restrict__ w_alpha,
                                               const float* __restrict__ feats,
                                               float* __restrict__ partial,
                                               float* __restrict__ zpart) {
    const int b   = blockIdx.x;
    const int c   = blockIdx.y;
    const int tid = threadIdx.x;
    const int lane = tid & 63;
    const int w    = tid >> 6;

    __shared__ float          s_w[CROWS];
    __shared__ float          s_zred[4];
    __shared__ unsigned short s_idx[CROWS + 4];
    __shared__ float          s_val[CROWS + 4];
    __shared__ int            s_cntreal;

    const float4* wh4 = (const float4*)(wah + (size_t)b * H);
    const float4* wa4 = (const float4*)w_alpha;
    float4 wh0 = wh4[lane], wh1 = wh4[lane + 64];
    float4 wa0 = wa4[lane], wa1 = wa4[lane + 64];

    const int     m0   = c * CROWS;
    const int*    mrow = mask + (size_t)b * M + m0;
    const float4* pb4  = (const float4*)(p_att + ((size_t)b * M + m0) * H);

    float zsum = 0.0f;
    for (int r = w * RPW; r < w * RPW + RPW; ++r) {
        float e = 0.0f;
        if (mrow[r] != 0) {                       // wave-uniform branch
            float4 p0 = pb4[(size_t)r * (H / 4) + lane];
            float4 p1 = pb4[(size_t)r * (H / 4) + 64 + lane];
            float s = fast_tanh(p0.x + wh0.x) * wa0.x
                    + fast_tanh(p0.y + wh0.y) * wa0.y
                    + fast_tanh(p0.z + wh0.z) * wa0.z
                    + fast_tanh(p0.w + wh0.w) * wa0.w
                    + fast_tanh(p1.x + wh1.x) * wa1.x
                    + fast_tanh(p1.y + wh1.y) * wa1.y
                    + fast_tanh(p1.z + wh1.z) * wa1.z
                    + fast_tanh(p1.w + wh1.w) * wa1.w;
#pragma unroll
            for (int off = 32; off > 0; off >>= 1)
                s += __shfl_xor(s, off);
            e = __expf(s);                        // uniform across lanes
        }
        if (lane == 0) s_w[r] = e;
        zsum += e;
    }
    if (lane == 0) s_zred[w] = zsum;
    __syncthreads();
    if (tid == 0)
        zpart[(size_t)c * B + b] = (s_zred[0] + s_zred[1]) + (s_zred[2] + s_zred[3]);

    // ordered compaction (wave 0); pads duplicate a real row with alpha=0
    if (tid < CROWS) {
        float a = s_w[tid];
        bool pred = (a != 0.0f);
        unsigned long long bal = __ballot(pred);
        int pos = __popcll(bal & ((1ull << lane) - 1ull));
        if (pred) { s_idx[pos] = (unsigned short)tid; s_val[pos] = a; }
        if (lane == 0) s_cntreal = __popcll(bal);
    }
    __syncthreads();
    const int cnt = s_cntreal;
    const int n   = (cnt + 3) & ~3;
    if (tid >= cnt && tid < n) {
        s_idx[tid] = (cnt > 0) ? s_idx[cnt - 1] : (unsigned short)0;
        s_val[tid] = 0.0f;
    }
    __syncthreads();

    // phase 2: wave w owns d-slice [w*512, (w+1)*512); 8 loads in flight
    const float4* fb4 = (const float4*)(feats + ((size_t)b * M + m0) * D)
                        + (size_t)w * 128 + lane;
    float4 acc0 = {0.f, 0.f, 0.f, 0.f}, acc1 = {0.f, 0.f, 0.f, 0.f};
    for (int i = 0; i < n; i += 4) {
        int   r0 = s_idx[i],     r1 = s_idx[i + 1];
        int   r2 = s_idx[i + 2], r3 = s_idx[i + 3];
        float v0 = s_val[i],     v1 = s_val[i + 1];
        float v2 = s_val[i + 2], v3 = s_val[i + 3];
        const float4* q0 = fb4 + (size_t)r0 * (D / 4);
        const float4* q1 = fb4 + (size_t)r1 * (D / 4);
        const float4* q2 = fb4 + (size_t)r2 * (D / 4);
        const float4* q3 = fb4 + (size_t)r3 * (D / 4);
        float4 f00 = q0[0], f01 = q0[64];
        float4 f10 = q1[0], f11 = q1[64];
        float4 f20 = q2[0], f21 = q2[64];
        float4 f30 = q3[0], f31 = q3[64];
        acc0.x += v0 * f00.x; acc0.y += v0 * f00.y; acc0.z += v0 * f00.z; acc0.w += v0 * f00.w;
        acc1.x += v0 * f01.x; acc1.y += v0 * f01.y; acc1.z += v0 * f01.z; acc1.w += v0 * f01.w;
        acc0.x += v1 * f10.x; acc0.y += v1 * f10.y; acc0.z += v1 * f10.z; acc0.w += v1 * f10.w;
        acc1.x += v1 * f11.x; acc1.y += v1 * f11.y; acc1.z += v1 * f11.z; acc1.w += v1 * f11.w;
        acc0.x += v2 * f20.x; acc0.y += v2 * f20.y; acc0.z += v2 * f20.z; acc0.w += v2 * f20.w;
        acc1.x += v2 * f21.x; acc1.y += v2 * f21.y; acc1.z += v2 * f21.z; acc1.w += v2 * f21.w;
        acc0.x += v3 * f30.x; acc0.y += v3 * f30.y; acc0.z += v3 * f30.z; acc0.w += v3 * f30.w;
        acc1.x += v3 * f31.x; acc1.y += v3 * f31.y; acc1.z += v3 * f31.z; acc1.w += v3 * f31.w;
    }
    float4* ob = (float4*)(partial + ((size_t)c * B + b) * D) + (size_t)w * 128 + lane;
    ob[0]  = acc0;
    ob[64] = acc1;
}

// out[b,d] = (sum_c partial[c][b][d]) / (sum_c zpart[c][b])
__global__ __launch_bounds__(256) void k_reduce(const float* __restrict__ partial,
                                                const float* __restrict__ zpart,
                                                float* __restrict__ out) {
    int i4 = blockIdx.x * 256 + threadIdx.x;   // float4 index over B*D/4
    int b  = i4 >> 9;                          // uniform per block (512 f4 per row)
    float Z = 0.0f;
#pragma unroll
    for (int c = 0; c < NCHUNK; ++c)
        Z += zpart[c * B + b];
    const float4* p4 = (const float4*)partial;
    float4 s = p4[i4];
#pragma unroll
    for (int c = 1; c < NCHUNK; ++c) {
        float4 v = p4[(size_t)c * (B * D / 4) + i4];
        s.x += v.x; s.y += v.y; s.z += v.z; s.w += v.w;
    }
    float inv = 1.0f / Z;
    float4 r = {s.x * inv, s.y * inv, s.z * inv, s.w * inv};
    ((float4*)out)[i4] = r;
}

extern "C" void kernel_launch(void* const* d_in, const int* in_sizes, int n_in,
                              void* d_out, int out_size, void* d_ws, size_t ws_size,
                              hipStream_t stream) {
    const float* h       = (const float*)d_in[0];
    const float* feats   = (const float*)d_in[1];
    const int*   mask    = (const int*)d_in[2];
    const float* p_att   = (const float*)d_in[3];
    const float* W_ah    = (const float*)d_in[4];
    const float* w_alpha = (const float*)d_in[5];
    float* out = (float*)d_out;

    float* ws      = (float*)d_ws;
    float* wah     = ws;                  // B*H floats
    float* zpart   = wah + B * H;         // NCHUNK*B floats
    float* partial = zpart + NCHUNK * B;  // NCHUNK*B*D floats (8MB)

    k_wah   <<<dim3(H / 8, B / 16), 256, 0, stream>>>(h, W_ah, wah);
    k_fused <<<dim3(B, NCHUNK), 256, 0, stream>>>(wah, p_att, mask, w_alpha, feats,
                                                  partial, zpart);
    k_reduce<<<dim3(B * D / 1024), 256, 0, stream>>>(partial, zpart, out);
}

// Round 8
// 76.689 us; speedup vs baseline: 3.6229x; 1.0253x over previous
//
#include <hip/hip_runtime.h>
#include <math.h>

#define B   64
#define M   1024
#define RNN 1024
#define H   512
#define D   2048

#define NCHUNK 16
#define CROWS  (M / NCHUNK)   // 64 rows per block
#define RPW    (CROWS / 4)    // 16 rows per wave

// tanh(x) = sign(x) * (1 - e^{-2|x|}) / (1 + e^{-2|x|}); rcp via v_rcp_f32 (~1 ulp)
__device__ __forceinline__ float fast_tanh(float x) {
    float ax = fabsf(x);
    float t  = __expf(-2.0f * ax);
    float r  = (1.0f - t) * __builtin_amdgcn_rcpf(1.0f + t);
    return copysignf(r, x);
}

// Tiled wah = h @ W^T. grid (H/8, B/16), 256 threads.
__global__ __launch_bounds__(256) void k_wah(const float* __restrict__ h,
                                             const float* __restrict__ W,
                                             float* __restrict__ wah) {
    const int tid = threadIdx.x, lane = tid & 63, w = tid >> 6;
    const int bt = blockIdx.y * 16;
    const int j0 = blockIdx.x * 8 + w * 2;

    __shared__ float s_h[16 * RNN];        // 64KB
    const float4* h4  = (const float4*)(h + (size_t)bt * RNN);
    float4*       sh4 = (float4*)s_h;
#pragma unroll
    for (int k = 0; k < 16; ++k)
        sh4[tid + k * 256] = h4[tid + k * 256];

    const float4* Wa = (const float4*)(W + (size_t)j0 * RNN);
    const float4* Wb = (const float4*)(W + (size_t)(j0 + 1) * RNN);
    float4 wa[4], wb[4];
#pragma unroll
    for (int k = 0; k < 4; ++k) { wa[k] = Wa[lane + 64 * k]; wb[k] = Wb[lane + 64 * k]; }
    __syncthreads();

    for (int b = 0; b < 16; ++b) {
        float d0 = 0.0f, d1 = 0.0f;
#pragma unroll
        for (int k = 0; k < 4; ++k) {
            float4 hv = sh4[b * 256 + lane + 64 * k];
            d0 += hv.x * wa[k].x + hv.y * wa[k].y + hv.z * wa[k].z + hv.w * wa[k].w;
            d1 += hv.x * wb[k].x + hv.y * wb[k].y + hv.z * wb[k].z + hv.w * wb[k].w;
        }
#pragma unroll
        for (int off = 32; off > 0; off >>= 1) {
            d0 += __shfl_xor(d0, off);
            d1 += __shfl_xor(d1, off);
        }
        if (lane == 0)
            *(float2*)(wah + (size_t)(bt + b) * H + j0) = make_float2(d0, d1);
    }
}

// Per-row interleaved fused kernel: each wave owns 16 rows and a full-D
// accumulator. Per unmasked row, p_att loads (2) and feats loads (8) are all
// issued before the logit chain resolves (feats addresses don't depend on
// alpha), so the latency-bound tanh/reduce hides under the feats stream and
// both HBM streams interleave from t=0 -- no chip-wide phase convoy.
__global__ __launch_bounds__(256, 4) void k_fused(const float* __restrict__ wah,
                                                  const float* __restrict__ p_att,
                                                  const int* __restrict__ mask,
                                                  const float* __restrict__ w_alpha,
                                                  const float* __restrict__ feats,
                                                  float* __restrict__ partial,
                                                  float* __restrict__ zpart) {
    const int b   = blockIdx.x;
    const int c   = blockIdx.y;
    const int tid = threadIdx.x;
    const int lane = tid & 63;
    const int w    = tid >> 6;

    __shared__ float s_acc[4][D];    // 32KB
    __shared__ float s_z[4];

    const float4* wh4 = (const float4*)(wah + (size_t)b * H);
    const float4* wa4 = (const float4*)w_alpha;
    float4 wh0 = wh4[lane], wh1 = wh4[lane + 64];
    float4 wa0 = wa4[lane], wa1 = wa4[lane + 64];

    const int     m0   = c * CROWS;
    const int*    mrow = mask + (size_t)b * M + m0;
    const float4* pb4  = (const float4*)(p_att + ((size_t)b * M + m0) * H);
    const float4* fb4  = (const float4*)(feats + ((size_t)b * M + m0) * D);

    float4 acc[8];
#pragma unroll
    for (int j = 0; j < 8; ++j) acc[j] = make_float4(0.f, 0.f, 0.f, 0.f);
    float zsum = 0.0f;

    for (int r = w * RPW; r < w * RPW + RPW; ++r) {
        if (mrow[r] == 0) continue;               // wave-uniform skip
        const float4* pr = pb4 + (size_t)r * (H / 4);
        const float4* fr = fb4 + (size_t)r * (D / 4) + lane;
        float4 p0 = pr[lane], p1 = pr[lane + 64];
        float4 f0 = fr[0],   f1 = fr[64],  f2 = fr[128], f3 = fr[192];
        float4 f4 = fr[256], f5 = fr[320], f6 = fr[384], f7 = fr[448];

        float s = fast_tanh(p0.x + wh0.x) * wa0.x
                + fast_tanh(p0.y + wh0.y) * wa0.y
                + fast_tanh(p0.z + wh0.z) * wa0.z
                + fast_tanh(p0.w + wh0.w) * wa0.w
                + fast_tanh(p1.x + wh1.x) * wa1.x
                + fast_tanh(p1.y + wh1.y) * wa1.y
                + fast_tanh(p1.z + wh1.z) * wa1.z
                + fast_tanh(p1.w + wh1.w) * wa1.w;
#pragma unroll
        for (int off = 32; off > 0; off >>= 1)
            s += __shfl_xor(s, off);
        float e = __expf(s);                      // uniform across lanes
        zsum += e;

        acc[0].x += e * f0.x; acc[0].y += e * f0.y; acc[0].z += e * f0.z; acc[0].w += e * f0.w;
        acc[1].x += e * f1.x; acc[1].y += e * f1.y; acc[1].z += e * f1.z; acc[1].w += e * f1.w;
        acc[2].x += e * f2.x; acc[2].y += e * f2.y; acc[2].z += e * f2.z; acc[2].w += e * f2.w;
        acc[3].x += e * f3.x; acc[3].y += e * f3.y; acc[3].z += e * f3.z; acc[3].w += e * f3.w;
        acc[4].x += e * f4.x; acc[4].y += e * f4.y; acc[4].z += e * f4.z; acc[4].w += e * f4.w;
        acc[5].x += e * f5.x; acc[5].y += e * f5.y; acc[5].z += e * f5.z; acc[5].w += e * f5.w;
        acc[6].x += e * f6.x; acc[6].y += e * f6.y; acc[6].z += e * f6.z; acc[6].w += e * f6.w;
        acc[7].x += e * f7.x; acc[7].y += e * f7.y; acc[7].z += e * f7.z; acc[7].w += e * f7.w;
    }

    // per-wave results -> LDS
#pragma unroll
    for (int j = 0; j < 8; ++j)
        *(float4*)&s_acc[w][j * 256 + lane * 4] = acc[j];
    if (lane == 0) s_z[w] = zsum;
    __syncthreads();

    if (tid == 0)
        zpart[(size_t)c * B + b] = (s_z[0] + s_z[1]) + (s_z[2] + s_z[3]);

    // cross-wave sum, stride-1 (conflict-free): thread owns d = k*256 + tid
    float* pout = partial + ((size_t)c * B + b) * D;
#pragma unroll
    for (int k = 0; k < 8; ++k) {
        int d = k * 256 + tid;
        pout[d] = (s_acc[0][d] + s_acc[1][d]) + (s_acc[2][d] + s_acc[3][d]);
    }
}

// out[b,d] = (sum_c partial[c][b][d]) / (sum_c zpart[c][b])
__global__ __launch_bounds__(256) void k_reduce(const float* __restrict__ partial,
                                                const float* __restrict__ zpart,
                                                float* __restrict__ out) {
    int i4 = blockIdx.x * 256 + threadIdx.x;   // float4 index over B*D/4
    int b  = i4 >> 9;                          // uniform per block
    float Z = 0.0f;
#pragma unroll
    for (int c = 0; c < NCHUNK; ++c)
        Z += zpart[c * B + b];
    const float4* p4 = (const float4*)partial;
    float4 s = p4[i4];
#pragma unroll
    for (int c = 1; c < NCHUNK; ++c) {
        float4 v = p4[(size_t)c * (B * D / 4) + i4];
        s.x += v.x; s.y += v.y; s.z += v.z; s.w += v.w;
    }
    float inv = 1.0f / Z;
    float4 r = {s.x * inv, s.y * inv, s.z * inv, s.w * inv};
    ((float4*)out)[i4] = r;
}

extern "C" void kernel_launch(void* const* d_in, const int* in_sizes, int n_in,
                              void* d_out, int out_size, void* d_ws, size_t ws_size,
                              hipStream_t stream) {
    const float* h       = (const float*)d_in[0];
    const float* feats   = (const float*)d_in[1];
    const int*   mask    = (const int*)d_in[2];
    const float* p_att   = (const float*)d_in[3];
    const float* W_ah    = (const float*)d_in[4];
    const float* w_alpha = (const float*)d_in[5];
    float* out = (float*)d_out;

    float* ws      = (float*)d_ws;
    float* wah     = ws;                  // B*H floats
    float* zpart   = wah + B * H;         // NCHUNK*B floats
    float* partial = zpart + NCHUNK * B;  // NCHUNK*B*D floats (8MB)

    k_wah   <<<dim3(H / 8, B / 16), 256, 0, stream>>>(h, W_ah, wah);
    k_fused <<<dim3(B, NCHUNK), 256, 0, stream>>>(wah, p_att, mask, w_alpha, feats,
                                                  partial, zpart);
    k_reduce<<<dim3(B * D / 1024), 256, 0, stream>>>(partial, zpart, out);
}